// Round 1
// baseline (851.992 us; speedup 1.0000x reference)
//
#include <hip/hip_runtime.h>

// SAGEConv: h_neigh = segment_mean(feat[src] -> dst); out = relu(feat@Ws^T + bs + h_neigh@Wn^T + bn)
// N=50000 nodes, E=800000 edges, D_in = D_out = 64, all fp32.

#define N_NODES 50000
#define N_EDGES 800000
#define D 64

// ---------------------------------------------------------------------------
// Kernel 1: edge scatter. One thread handles (edge, 4 contiguous dims).
// 16 threads per edge; lane (t&15)==0 also bumps the degree counter.
// ---------------------------------------------------------------------------
__global__ __launch_bounds__(256) void sage_scatter(
    const float* __restrict__ feat,
    const int* __restrict__ src,
    const int* __restrict__ dst,
    float* __restrict__ neigh_sum,   // [N_NODES * D], pre-zeroed
    float* __restrict__ deg)         // [N_NODES], pre-zeroed
{
    const long long t = (long long)blockIdx.x * blockDim.x + threadIdx.x;
    const long long total = (long long)N_EDGES * (D / 4);
    if (t >= total) return;
    const int e  = (int)(t >> 4);        // edge index
    const int d4 = (int)(t & 15) << 2;   // dim offset (0,4,...,60)
    const int s  = src[e];
    const int dd = dst[e];
    const float4 v = *reinterpret_cast<const float4*>(&feat[(long long)s * D + d4]);
    float* base = &neigh_sum[(long long)dd * D + d4];
    atomicAdd(base + 0, v.x);
    atomicAdd(base + 1, v.y);
    atomicAdd(base + 2, v.z);
    atomicAdd(base + 3, v.w);
    if ((t & 15) == 0) atomicAdd(&deg[dd], 1.0f);
}

// ---------------------------------------------------------------------------
// Kernel 2: per-node transform.
// Block = 256 threads = 4 nodes x 64 output dims.
// Weights staged TRANSPOSED in LDS with +1 pad (wT[i][j] = W[j*64+i]) so the
// inner-loop read wT[i][j] is conflict-free (lanes j consecutive).
// ---------------------------------------------------------------------------
__global__ __launch_bounds__(256) void sage_transform(
    const float* __restrict__ feat,
    const float* __restrict__ neigh_sum,
    const float* __restrict__ deg,
    const float* __restrict__ W_self,
    const float* __restrict__ b_self,
    const float* __restrict__ W_neigh,
    const float* __restrict__ b_neigh,
    const int* __restrict__ act_flag,
    float* __restrict__ out)
{
    __shared__ float wsT[D][D + 1];
    __shared__ float wnT[D][D + 1];
    __shared__ float bsum[D];
    __shared__ float f_lds[4][D];
    __shared__ float h_lds[4][D];

    const int tid = threadIdx.x;

    // Stage transposed weights. idx = j*64 + i  ->  wT[i][j].
    for (int idx = tid; idx < D * D; idx += 256) {
        const int j = idx >> 6;
        const int i = idx & 63;
        wsT[i][j] = W_self[idx];
        wnT[i][j] = W_neigh[idx];
    }
    if (tid < D) bsum[tid] = b_self[tid] + b_neigh[tid];
    __syncthreads();

    const int act = act_flag[0];   // uniform scalar read (cached)
    const int ln = tid >> 6;       // local node 0..3
    const int j  = tid & 63;       // output dim

    const int n = blockIdx.x * 4 + ln;   // grid sized so 4*gridDim >= N_NODES
    if (n < N_NODES) {
        // Stage this node's feat row and mean-aggregated neighbor row.
        f_lds[ln][j] = feat[(long long)n * D + j];
        const float dg = deg[n];
        h_lds[ln][j] = (dg > 0.0f) ? neigh_sum[(long long)n * D + j] / dg : 0.0f;
    }
    __syncthreads();

    if (n < N_NODES) {
        float acc = bsum[j];
        #pragma unroll
        for (int i = 0; i < D; ++i) {
            acc += f_lds[ln][i] * wsT[i][j];
            acc += h_lds[ln][i] * wnT[i][j];
        }
        if (act) acc = fmaxf(acc, 0.0f);
        out[(long long)n * D + j] = acc;
    }
}

// ---------------------------------------------------------------------------
extern "C" void kernel_launch(void* const* d_in, const int* in_sizes, int n_in,
                              void* d_out, int out_size, void* d_ws, size_t ws_size,
                              hipStream_t stream)
{
    const float* feat    = (const float*)d_in[0];
    const int*   src     = (const int*)  d_in[1];
    const int*   dst     = (const int*)  d_in[2];
    const float* W_self  = (const float*)d_in[3];
    const float* b_self  = (const float*)d_in[4];
    const float* W_neigh = (const float*)d_in[5];
    const float* b_neigh = (const float*)d_in[6];
    const int*   actf    = (const int*)  d_in[7];
    float* out = (float*)d_out;

    float* neigh_sum = (float*)d_ws;                      // N_NODES * D floats
    float* deg       = neigh_sum + (size_t)N_NODES * D;   // N_NODES floats

    const size_t zero_bytes = ((size_t)N_NODES * D + N_NODES) * sizeof(float);
    hipMemsetAsync(d_ws, 0, zero_bytes, stream);

    // Scatter: E * 16 threads.
    {
        const long long total = (long long)N_EDGES * (D / 4);
        const int block = 256;
        const int grid = (int)((total + block - 1) / block);
        sage_scatter<<<grid, block, 0, stream>>>(feat, src, dst, neigh_sum, deg);
    }

    // Transform: 4 nodes per 256-thread block.
    {
        const int block = 256;
        const int grid = (N_NODES + 3) / 4;
        sage_transform<<<grid, block, 0, stream>>>(feat, neigh_sum, deg,
                                                   W_self, b_self, W_neigh, b_neigh,
                                                   actf, out);
    }
}

// Round 2
// 328.009 us; speedup vs baseline: 2.5975x; 2.5975x over previous
//
#include <hip/hip_runtime.h>

// SAGEConv: h_neigh = segment_mean(feat[src] -> dst); out = relu(feat@Ws^T + bs + h_neigh@Wn^T + bn)
// N=50000 nodes, E=800000 edges, D_in = D_out = 64, fp32.
//
// Strategy (round 2): replace 51.2M f32 device atomics (825 MB of memory-side
// atomic traffic, 718 us) with a device-built CSR (counting sort, 1.6M int
// atomics) + an atomic-free gather-mean fused with the dense transform.

#define N_NODES 50000
#define N_EDGES 800000
#define D 64
#define SCAN_BLOCK 1024
#define NUM_SCAN_BLOCKS ((N_NODES + SCAN_BLOCK - 1) / SCAN_BLOCK)   // 49

// ---------------------------------------------------------------------------
// K1: in-degree histogram (int atomics, 800k ops)
// ---------------------------------------------------------------------------
__global__ __launch_bounds__(256) void k_hist(const int* __restrict__ dst,
                                              int* __restrict__ deg)
{
    const int e = blockIdx.x * 256 + threadIdx.x;
    if (e < N_EDGES) atomicAdd(&deg[dst[e]], 1);
}

// ---------------------------------------------------------------------------
// K2: per-block exclusive scan (Hillis-Steele over 1024) + block sums
// ---------------------------------------------------------------------------
__global__ __launch_bounds__(SCAN_BLOCK) void k_scan_blocks(
    const int* __restrict__ deg,
    int* __restrict__ row_start,
    int* __restrict__ blocksums)
{
    __shared__ int s[SCAN_BLOCK];
    const int t = threadIdx.x;
    const int i = blockIdx.x * SCAN_BLOCK + t;
    const int orig = (i < N_NODES) ? deg[i] : 0;
    s[t] = orig;
    __syncthreads();
    for (int off = 1; off < SCAN_BLOCK; off <<= 1) {
        const int add = (t >= off) ? s[t - off] : 0;
        __syncthreads();
        s[t] += add;
        __syncthreads();
    }
    if (i < N_NODES) row_start[i] = s[t] - orig;       // exclusive within block
    if (t == SCAN_BLOCK - 1) blocksums[blockIdx.x] = s[t];
}

// ---------------------------------------------------------------------------
// K3: add scanned block offsets (each block redundantly sums <=48 ints in LDS)
// ---------------------------------------------------------------------------
__global__ __launch_bounds__(SCAN_BLOCK) void k_scan_add(
    int* __restrict__ row_start, const int* __restrict__ blocksums)
{
    __shared__ int bs[64];
    const int t = threadIdx.x;
    if (t < 64) bs[t] = (t < NUM_SCAN_BLOCKS) ? blocksums[t] : 0;
    __syncthreads();
    int offset = 0;
    for (int k = 0; k < (int)blockIdx.x; ++k) offset += bs[k];  // broadcast reads
    const int i = blockIdx.x * SCAN_BLOCK + t;
    if (i < N_NODES) row_start[i] += offset;
}

// ---------------------------------------------------------------------------
// K4: fill CSR slots (int atomics for per-dst rank, 800k ops)
// ---------------------------------------------------------------------------
__global__ __launch_bounds__(256) void k_fill(
    const int* __restrict__ src, const int* __restrict__ dst,
    const int* __restrict__ row_start, int* __restrict__ cursor,
    int* __restrict__ src_sorted)
{
    const int e = blockIdx.x * 256 + threadIdx.x;
    if (e >= N_EDGES) return;
    const int d = dst[e];
    const int r = atomicAdd(&cursor[d], 1);
    src_sorted[row_start[d] + r] = src[e];
}

// ---------------------------------------------------------------------------
// K5: fused gather-mean + dense transform.
// Block = 256 threads = 4 waves = 4 nodes (50000 = 4 * 12500 exactly).
// Wave w owns node n; lane j owns output/input dim j.
// Gather loop: one coalesced 256B read of feat[src] per edge, no atomics.
// Transform: weights staged transposed in LDS (+1 pad), conflict-free.
// ---------------------------------------------------------------------------
__global__ __launch_bounds__(256) void k_gather_transform(
    const float* __restrict__ feat,
    const int* __restrict__ row_start,
    const int* __restrict__ deg,
    const int* __restrict__ src_sorted,
    const float* __restrict__ W_self,
    const float* __restrict__ b_self,
    const float* __restrict__ W_neigh,
    const float* __restrict__ b_neigh,
    const int* __restrict__ act_flag,
    float* __restrict__ out)
{
    __shared__ float wsT[D][D + 1];
    __shared__ float wnT[D][D + 1];
    __shared__ float bsum[D];
    __shared__ float f_lds[4][D];
    __shared__ float h_lds[4][D];

    const int tid = threadIdx.x;

    for (int idx = tid; idx < D * D; idx += 256) {
        const int j = idx >> 6;     // output row of W
        const int i = idx & 63;     // input col
        wsT[i][j] = W_self[idx];
        wnT[i][j] = W_neigh[idx];
    }
    if (tid < D) bsum[tid] = b_self[tid] + b_neigh[tid];

    const int w = tid >> 6;         // wave / local node
    const int j = tid & 63;         // dim
    const int n = blockIdx.x * 4 + w;   // < 50000 always

    // Gather-mean (no barrier needed yet; LDS weights not read here)
    const int start = row_start[n];
    const int dg    = deg[n];
    float acc = 0.0f;
    for (int k = 0; k < dg; ++k) {
        const int s = src_sorted[start + k];           // wave-uniform broadcast
        acc += feat[(long long)s * D + j];             // coalesced 256B/wave
    }
    const float inv = (dg > 0) ? (1.0f / (float)dg) : 0.0f;

    h_lds[w][j] = acc * inv;
    f_lds[w][j] = feat[(long long)n * D + j];
    __syncthreads();

    const int act = act_flag[0];
    float o = bsum[j];
    #pragma unroll
    for (int i = 0; i < D; ++i) {
        o = fmaf(f_lds[w][i], wsT[i][j], o);
        o = fmaf(h_lds[w][i], wnT[i][j], o);
    }
    if (act) o = fmaxf(o, 0.0f);
    out[(long long)n * D + j] = o;
}

// ---------------------------------------------------------------------------
extern "C" void kernel_launch(void* const* d_in, const int* in_sizes, int n_in,
                              void* d_out, int out_size, void* d_ws, size_t ws_size,
                              hipStream_t stream)
{
    const float* feat    = (const float*)d_in[0];
    const int*   src     = (const int*)  d_in[1];
    const int*   dst     = (const int*)  d_in[2];
    const float* W_self  = (const float*)d_in[3];
    const float* b_self  = (const float*)d_in[4];
    const float* W_neigh = (const float*)d_in[5];
    const float* b_neigh = (const float*)d_in[6];
    const int*   actf    = (const int*)  d_in[7];
    float* out = (float*)d_out;

    // Workspace layout (bytes):
    //   [0,        200000)  deg        int[50000]
    //   [200000,   400000)  row_start  int[50000]
    //   [400000,   400256)  blocksums  int[64]
    //   [400256,   600256)  cursor     int[50000]
    //   [600256,  3800256)  src_sorted int[800000]
    char* base = (char*)d_ws;
    int* deg        = (int*)(base);
    int* row_start  = (int*)(base + 200000);
    int* blocksums  = (int*)(base + 400000);
    int* cursor     = (int*)(base + 400256);
    int* src_sorted = (int*)(base + 600256);

    // Zero deg + cursor (covers row_start/blocksums too; they're overwritten).
    hipMemsetAsync(d_ws, 0, 600256, stream);

    const int eblocks = (N_EDGES + 255) / 256;   // 3125
    k_hist<<<eblocks, 256, 0, stream>>>(dst, deg);
    k_scan_blocks<<<NUM_SCAN_BLOCKS, SCAN_BLOCK, 0, stream>>>(deg, row_start, blocksums);
    k_scan_add<<<NUM_SCAN_BLOCKS, SCAN_BLOCK, 0, stream>>>(row_start, blocksums);
    k_fill<<<eblocks, 256, 0, stream>>>(src, dst, row_start, cursor, src_sorted);
    k_gather_transform<<<N_NODES / 4, 256, 0, stream>>>(
        feat, row_start, deg, src_sorted,
        W_self, b_self, W_neigh, b_neigh, actf, out);
}

// Round 4
// 296.471 us; speedup vs baseline: 2.8738x; 1.1064x over previous
//
#include <hip/hip_runtime.h>

// SAGEConv: h_neigh = segment_mean(feat[src] -> dst); out = relu(feat@Ws^T + bs + h_neigh@Wn^T + bn)
// N=50000, E=800000, D_in = D_out = 64, fp32.
//
// Round 3 (resubmit; prior attempt hit GPU-broker timeout, never ran):
// (a) transform re-mapped to lane=node with s_load (scalar) weights --
// kills the ~256 ds_read/node LDS bottleneck; (b) gather uses 16-lane/edge
// float4 loads (4 edges in flight per wave); (c) CSR scan in one block;
// (d) hist/fill vectorized int4.

#define N_NODES 50000
#define N_EDGES 800000
#define D 64
#define NPB 64                   // nodes per fused block (4 waves x 16 outputs)
#define SCAN_T 1024
#define SCAN_CHUNK ((N_NODES + SCAN_T - 1) / SCAN_T)   // 49

// ---------------------------------------------------------------------------
// K1: in-degree histogram (4 edges/thread, int atomics)
// ---------------------------------------------------------------------------
__global__ __launch_bounds__(256) void k_hist(const int* __restrict__ dst,
                                              int* __restrict__ deg)
{
    const int e4 = blockIdx.x * 256 + threadIdx.x;
    if (e4 >= N_EDGES / 4) return;
    const int4 d = *reinterpret_cast<const int4*>(dst + e4 * 4);
    atomicAdd(&deg[d.x], 1);
    atomicAdd(&deg[d.y], 1);
    atomicAdd(&deg[d.z], 1);
    atomicAdd(&deg[d.w], 1);
}

// ---------------------------------------------------------------------------
// K2: single-block exclusive scan of deg[50000] -> row_start
// ---------------------------------------------------------------------------
__global__ __launch_bounds__(SCAN_T) void k_scan(const int* __restrict__ deg,
                                                 int* __restrict__ row_start)
{
    __shared__ int ssum[SCAN_T];
    const int t  = threadIdx.x;
    const int b0 = t * SCAN_CHUNK;
    const int b1 = (b0 + SCAN_CHUNK < N_NODES) ? b0 + SCAN_CHUNK : N_NODES;
    int s = 0;
    for (int i = b0; i < b1; ++i) s += deg[i];
    ssum[t] = s;
    __syncthreads();
    for (int off = 1; off < SCAN_T; off <<= 1) {
        const int add = (t >= off) ? ssum[t - off] : 0;
        __syncthreads();
        ssum[t] += add;
        __syncthreads();
    }
    int prefix = ssum[t] - s;          // exclusive
    for (int i = b0; i < b1; ++i) { row_start[i] = prefix; prefix += deg[i]; }
}

// ---------------------------------------------------------------------------
// K3: fill CSR slots (4 edges/thread; order within a node is irrelevant)
// ---------------------------------------------------------------------------
__global__ __launch_bounds__(256) void k_fill(const int* __restrict__ src,
                                              const int* __restrict__ dst,
                                              const int* __restrict__ row_start,
                                              int* __restrict__ cursor,
                                              int* __restrict__ src_sorted)
{
    const int e4 = blockIdx.x * 256 + threadIdx.x;
    if (e4 >= N_EDGES / 4) return;
    const int4 s = *reinterpret_cast<const int4*>(src + e4 * 4);
    const int4 d = *reinterpret_cast<const int4*>(dst + e4 * 4);
    int r;
    r = atomicAdd(&cursor[d.x], 1); src_sorted[row_start[d.x] + r] = s.x;
    r = atomicAdd(&cursor[d.y], 1); src_sorted[row_start[d.y] + r] = s.y;
    r = atomicAdd(&cursor[d.z], 1); src_sorted[row_start[d.z] + r] = s.z;
    r = atomicAdd(&cursor[d.w], 1); src_sorted[row_start[d.w] + r] = s.w;
}

// ---------------------------------------------------------------------------
// K4: fused gather-mean + transform. Block = 256 threads = 4 waves, 64 nodes.
// Gather: wave w handles 16 nodes; 16 lanes/edge, float4 loads (4 edges in
//   flight), shfl-broadcast indices, xor-reduce across slot groups.
// Transform: lane = node, wave w computes outputs j in [16w,16w+16);
//   weights via wave-uniform contiguous scalar loads (s_load_dwordx16),
//   f/h columns from LDS ([i][n] layout, +1 pad, conflict-free).
// Output: LDS transpose round-trip (reuse fT) -> coalesced stores.
// ---------------------------------------------------------------------------
__global__ __launch_bounds__(256) void k_fused(
    const float* __restrict__ feat,
    const int* __restrict__ row_start,
    const int* __restrict__ deg,
    const int* __restrict__ src_sorted,
    const float* __restrict__ W_self,
    const float* __restrict__ b_self,
    const float* __restrict__ W_neigh,
    const float* __restrict__ b_neigh,
    const int* __restrict__ act_flag,
    float* __restrict__ out)
{
    __shared__ float fT[D][NPB + 1];   // fT[i][n_local], +1 pad
    __shared__ float hT[D][NPB + 1];

    const int tid  = threadIdx.x;
    const int lane = tid & 63;
    const int w    = __builtin_amdgcn_readfirstlane(tid >> 6);   // wave 0..3, SGPR
    const int n_base = blockIdx.x * NPB;

    // ---- stage fT (transposed feat tile), coalesced reads ----
    #pragma unroll
    for (int r = 0; r < 16; ++r) {
        const int idx = r * 256 + tid;
        const int nl  = idx >> 6;
        const int i   = idx & 63;
        const int n   = n_base + nl;
        fT[i][nl] = (n < N_NODES) ? feat[n * D + i] : 0.0f;
    }

    // ---- gather-mean: wave w -> nodes nl = 16w .. 16w+15 ----
    const int slot = lane >> 4;          // edge slot 0..3
    const int d4   = (lane & 15) << 2;   // dim quad 0,4,...,60
    for (int q = 0; q < 16; ++q) {
        const int nl = (w << 4) + q;
        const int n  = n_base + nl;      // wave-uniform
        float4 a = make_float4(0.f, 0.f, 0.f, 0.f);
        int dg = 0;
        if (n < N_NODES) {
            const int start = row_start[n];   // uniform -> s_load
            dg = deg[n];
            int my_idx = 0;
            if (lane < dg) my_idx = src_sorted[start + lane];   // one coalesced load
            const int kmax  = (dg < 64) ? dg : 64;
            const int iters = (kmax + 3) >> 2;                  // uniform trip count
            #pragma unroll 2
            for (int t2 = 0; t2 < iters; ++t2) {
                const int k  = (t2 << 2) + slot;
                const int kc = (k < kmax) ? k : 0;
                const int s  = __shfl(my_idx, kc);
                const float m = (k < kmax) ? 1.0f : 0.0f;
                const float4 v = *reinterpret_cast<const float4*>(feat + s * D + d4);
                a.x = fmaf(m, v.x, a.x);
                a.y = fmaf(m, v.y, a.y);
                a.z = fmaf(m, v.z, a.z);
                a.w = fmaf(m, v.w, a.w);
            }
            for (int k = 64 + slot; k < dg; k += 4) {           // dg>64: ~never
                const int s = src_sorted[start + k];
                const float4 v = *reinterpret_cast<const float4*>(feat + s * D + d4);
                a.x += v.x; a.y += v.y; a.z += v.z; a.w += v.w;
            }
        }
        // reduce across the 4 slot groups
        a.x += __shfl_xor(a.x, 16); a.x += __shfl_xor(a.x, 32);
        a.y += __shfl_xor(a.y, 16); a.y += __shfl_xor(a.y, 32);
        a.z += __shfl_xor(a.z, 16); a.z += __shfl_xor(a.z, 32);
        a.w += __shfl_xor(a.w, 16); a.w += __shfl_xor(a.w, 32);
        const float inv = (dg > 0) ? (1.0f / (float)dg) : 0.0f;
        // lane writes component `slot` of its dim quad (2 lanes/bank = free)
        const float v = (slot & 1) ? ((slot & 2) ? a.w : a.y)
                                   : ((slot & 2) ? a.z : a.x);
        hT[d4 + slot][nl] = v * inv;
    }
    __syncthreads();

    // ---- transform: lane = node, wave w -> outputs j = 16w + jj ----
    const int nl = lane;
    const int act = act_flag[0];                 // uniform
    float acc[16];
    #pragma unroll
    for (int jj = 0; jj < 16; ++jj) {
        const int j = (w << 4) + jj;
        acc[jj] = b_self[j] + b_neigh[j];        // uniform s_loads
    }
    #pragma unroll
    for (int c = 0; c < 4; ++c) {                // i-chunks of 16
        float fr[16], hr[16];
        #pragma unroll
        for (int u = 0; u < 16; ++u) {
            fr[u] = fT[c * 16 + u][nl];          // conflict-free b32
            hr[u] = hT[c * 16 + u][nl];
        }
        #pragma unroll
        for (int jj = 0; jj < 16; ++jj) {
            const int j = (w << 4) + jj;
            const float* ws = &W_self [j * D + c * 16];   // uniform contiguous
            const float* wn = &W_neigh[j * D + c * 16];   // -> s_load_dwordx16
            #pragma unroll
            for (int u = 0; u < 16; ++u) {
                acc[jj] = fmaf(fr[u], ws[u], acc[jj]);
                acc[jj] = fmaf(hr[u], wn[u], acc[jj]);
            }
        }
    }

    // ---- output via LDS transpose (reuse fT), coalesced stores ----
    __syncthreads();                             // all waves done reading fT
    #pragma unroll
    for (int jj = 0; jj < 16; ++jj) {
        float o = acc[jj];
        o = act ? fmaxf(o, 0.0f) : o;
        fT[(w << 4) + jj][nl] = o;               // oT[j][n]
    }
    __syncthreads();
    #pragma unroll
    for (int r = 0; r < 16; ++r) {
        const int idx = r * 256 + tid;
        const int nl2 = idx >> 6;
        const int j   = idx & 63;
        const int n2  = n_base + nl2;
        if (n2 < N_NODES) out[n2 * D + j] = fT[j][nl2];
    }
}

// ---------------------------------------------------------------------------
extern "C" void kernel_launch(void* const* d_in, const int* in_sizes, int n_in,
                              void* d_out, int out_size, void* d_ws, size_t ws_size,
                              hipStream_t stream)
{
    const float* feat    = (const float*)d_in[0];
    const int*   src     = (const int*)  d_in[1];
    const int*   dst     = (const int*)  d_in[2];
    const float* W_self  = (const float*)d_in[3];
    const float* b_self  = (const float*)d_in[4];
    const float* W_neigh = (const float*)d_in[5];
    const float* b_neigh = (const float*)d_in[6];
    const int*   actf    = (const int*)  d_in[7];
    float* out = (float*)d_out;

    // Workspace layout (bytes):
    //   [0,       200000)  deg        int[50000]
    //   [200000,  400000)  cursor     int[50000]
    //   [400000,  600000)  row_start  int[50000]
    //   [600000, 3800000)  src_sorted int[800000]
    char* base = (char*)d_ws;
    int* deg        = (int*)(base);
    int* cursor     = (int*)(base + 200000);
    int* row_start  = (int*)(base + 400000);
    int* src_sorted = (int*)(base + 600000);

    hipMemsetAsync(d_ws, 0, 400000, stream);     // deg + cursor

    const int e4blocks = (N_EDGES / 4 + 255) / 256;          // 782
    k_hist<<<e4blocks, 256, 0, stream>>>(dst, deg);
    k_scan<<<1, SCAN_T, 0, stream>>>(deg, row_start);
    k_fill<<<e4blocks, 256, 0, stream>>>(src, dst, row_start, cursor, src_sorted);

    const int fblocks = (N_NODES + NPB - 1) / NPB;           // 782
    k_fused<<<fblocks, 256, 0, stream>>>(feat, row_start, deg, src_sorted,
                                         W_self, b_self, W_neigh, b_neigh,
                                         actf, out);
}

// Round 7
// 195.588 us; speedup vs baseline: 4.3561x; 1.5158x over previous
//
#include <hip/hip_runtime.h>

// SAGEConv: h_neigh = segment_mean(feat[src] -> dst); out = relu(feat@Ws^T + bs + h_neigh@Wn^T + bn)
// N=50000, E=800000, D_in = D_out = 64, fp32.
//
// Round 5 re-resubmit (broker timeouts x2, never ran): (a) single-block scan
// (77us @ 0.14% occupancy) -> hierarchical 49-block scan (~4us); (b) rank-
// capture in histogram (atomicAdd return value = rank) makes k_fill
// atomic-free; (c) memset shrinks to deg only.

#define N_NODES 50000
#define N_EDGES 800000
#define D 64
#define NPB 64                    // nodes per fused block (4 waves x 16 outputs)
#define SCAN_BLOCK 1024
#define NUM_SCAN_BLOCKS ((N_NODES + SCAN_BLOCK - 1) / SCAN_BLOCK)   // 49

// ---------------------------------------------------------------------------
// K1: in-degree histogram + per-edge rank capture (4 edges/thread)
// ---------------------------------------------------------------------------
__global__ __launch_bounds__(256) void k_hist(const int* __restrict__ dst,
                                              int* __restrict__ deg,
                                              int* __restrict__ rank)
{
    const int e4 = blockIdx.x * 256 + threadIdx.x;
    if (e4 >= N_EDGES / 4) return;
    const int4 d = *reinterpret_cast<const int4*>(dst + e4 * 4);
    int4 r;
    r.x = atomicAdd(&deg[d.x], 1);
    r.y = atomicAdd(&deg[d.y], 1);
    r.z = atomicAdd(&deg[d.z], 1);
    r.w = atomicAdd(&deg[d.w], 1);
    *reinterpret_cast<int4*>(rank + e4 * 4) = r;
}

// ---------------------------------------------------------------------------
// K2a: per-block exclusive scan (Hillis-Steele over 1024) + block sums
// ---------------------------------------------------------------------------
__global__ __launch_bounds__(SCAN_BLOCK) void k_scan_blocks(
    const int* __restrict__ deg,
    int* __restrict__ row_start,
    int* __restrict__ blocksums)
{
    __shared__ int s[SCAN_BLOCK];
    const int t = threadIdx.x;
    const int i = blockIdx.x * SCAN_BLOCK + t;
    const int orig = (i < N_NODES) ? deg[i] : 0;
    s[t] = orig;
    __syncthreads();
    for (int off = 1; off < SCAN_BLOCK; off <<= 1) {
        const int add = (t >= off) ? s[t - off] : 0;
        __syncthreads();
        s[t] += add;
        __syncthreads();
    }
    if (i < N_NODES) row_start[i] = s[t] - orig;       // exclusive within block
    if (t == SCAN_BLOCK - 1) blocksums[blockIdx.x] = s[t];
}

// ---------------------------------------------------------------------------
// K2b: add scanned block offsets (each block redundantly sums <=48 ints)
// ---------------------------------------------------------------------------
__global__ __launch_bounds__(SCAN_BLOCK) void k_scan_add(
    int* __restrict__ row_start, const int* __restrict__ blocksums)
{
    __shared__ int bs[64];
    const int t = threadIdx.x;
    if (t < 64) bs[t] = (t < NUM_SCAN_BLOCKS) ? blocksums[t] : 0;
    __syncthreads();
    int offset = 0;
    for (int k = 0; k < (int)blockIdx.x; ++k) offset += bs[k];  // broadcast reads
    const int i = blockIdx.x * SCAN_BLOCK + t;
    if (i < N_NODES) row_start[i] += offset;
}

// ---------------------------------------------------------------------------
// K3: fill CSR slots — ATOMIC-FREE (rank precomputed in k_hist)
// ---------------------------------------------------------------------------
__global__ __launch_bounds__(256) void k_fill(const int* __restrict__ src,
                                              const int* __restrict__ dst,
                                              const int* __restrict__ rank,
                                              const int* __restrict__ row_start,
                                              int* __restrict__ src_sorted)
{
    const int e4 = blockIdx.x * 256 + threadIdx.x;
    if (e4 >= N_EDGES / 4) return;
    const int4 s = *reinterpret_cast<const int4*>(src + e4 * 4);
    const int4 d = *reinterpret_cast<const int4*>(dst + e4 * 4);
    const int4 r = *reinterpret_cast<const int4*>(rank + e4 * 4);
    src_sorted[row_start[d.x] + r.x] = s.x;
    src_sorted[row_start[d.y] + r.y] = s.y;
    src_sorted[row_start[d.z] + r.z] = s.z;
    src_sorted[row_start[d.w] + r.w] = s.w;
}

// ---------------------------------------------------------------------------
// K4: fused gather-mean + transform. Block = 256 threads = 4 waves, 64 nodes.
// Gather: wave w handles 16 nodes; 16 lanes/edge, float4 loads (4 edges in
//   flight), shfl-broadcast indices, xor-reduce across slot groups.
// Transform: lane = node, wave w computes outputs j in [16w,16w+16);
//   weights via wave-uniform contiguous scalar loads (s_load_dwordx16),
//   f/h columns from LDS ([i][n] layout, +1 pad, conflict-free).
// Output: LDS transpose round-trip (reuse fT) -> coalesced stores.
// ---------------------------------------------------------------------------
__global__ __launch_bounds__(256) void k_fused(
    const float* __restrict__ feat,
    const int* __restrict__ row_start,
    const int* __restrict__ deg,
    const int* __restrict__ src_sorted,
    const float* __restrict__ W_self,
    const float* __restrict__ b_self,
    const float* __restrict__ W_neigh,
    const float* __restrict__ b_neigh,
    const int* __restrict__ act_flag,
    float* __restrict__ out)
{
    __shared__ float fT[D][NPB + 1];   // fT[i][n_local], +1 pad
    __shared__ float hT[D][NPB + 1];

    const int tid  = threadIdx.x;
    const int lane = tid & 63;
    const int w    = __builtin_amdgcn_readfirstlane(tid >> 6);   // wave 0..3, SGPR
    const int n_base = blockIdx.x * NPB;

    // ---- stage fT (transposed feat tile), coalesced reads ----
    #pragma unroll
    for (int r = 0; r < 16; ++r) {
        const int idx = r * 256 + tid;
        const int nl  = idx >> 6;
        const int i   = idx & 63;
        const int n   = n_base + nl;
        fT[i][nl] = (n < N_NODES) ? feat[n * D + i] : 0.0f;
    }

    // ---- gather-mean: wave w -> nodes nl = 16w .. 16w+15 ----
    const int slot = lane >> 4;          // edge slot 0..3
    const int d4   = (lane & 15) << 2;   // dim quad 0,4,...,60
    for (int q = 0; q < 16; ++q) {
        const int nl = (w << 4) + q;
        const int n  = n_base + nl;      // wave-uniform
        float4 a = make_float4(0.f, 0.f, 0.f, 0.f);
        int dg = 0;
        if (n < N_NODES) {
            const int start = row_start[n];   // uniform -> s_load
            dg = deg[n];
            int my_idx = 0;
            if (lane < dg) my_idx = src_sorted[start + lane];   // one coalesced load
            const int kmax  = (dg < 64) ? dg : 64;
            const int iters = (kmax + 3) >> 2;                  // uniform trip count
            #pragma unroll 2
            for (int t2 = 0; t2 < iters; ++t2) {
                const int k  = (t2 << 2) + slot;
                const int kc = (k < kmax) ? k : 0;
                const int s  = __shfl(my_idx, kc);
                const float m = (k < kmax) ? 1.0f : 0.0f;
                const float4 v = *reinterpret_cast<const float4*>(feat + s * D + d4);
                a.x = fmaf(m, v.x, a.x);
                a.y = fmaf(m, v.y, a.y);
                a.z = fmaf(m, v.z, a.z);
                a.w = fmaf(m, v.w, a.w);
            }
            for (int k = 64 + slot; k < dg; k += 4) {           // dg>64: ~never
                const int s = src_sorted[start + k];
                const float4 v = *reinterpret_cast<const float4*>(feat + s * D + d4);
                a.x += v.x; a.y += v.y; a.z += v.z; a.w += v.w;
            }
        }
        // reduce across the 4 slot groups
        a.x += __shfl_xor(a.x, 16); a.x += __shfl_xor(a.x, 32);
        a.y += __shfl_xor(a.y, 16); a.y += __shfl_xor(a.y, 32);
        a.z += __shfl_xor(a.z, 16); a.z += __shfl_xor(a.z, 32);
        a.w += __shfl_xor(a.w, 16); a.w += __shfl_xor(a.w, 32);
        const float inv = (dg > 0) ? (1.0f / (float)dg) : 0.0f;
        // lane writes component `slot` of its dim quad (2 lanes/bank = free)
        const float v = (slot & 1) ? ((slot & 2) ? a.w : a.y)
                                   : ((slot & 2) ? a.z : a.x);
        hT[d4 + slot][nl] = v * inv;
    }
    __syncthreads();

    // ---- transform: lane = node, wave w -> outputs j = 16w + jj ----
    const int nl = lane;
    const int act = act_flag[0];                 // uniform
    float acc[16];
    #pragma unroll
    for (int jj = 0; jj < 16; ++jj) {
        const int j = (w << 4) + jj;
        acc[jj] = b_self[j] + b_neigh[j];        // uniform s_loads
    }
    #pragma unroll
    for (int c = 0; c < 4; ++c) {                // i-chunks of 16
        float fr[16], hr[16];
        #pragma unroll
        for (int u = 0; u < 16; ++u) {
            fr[u] = fT[c * 16 + u][nl];          // conflict-free b32
            hr[u] = hT[c * 16 + u][nl];
        }
        #pragma unroll
        for (int jj = 0; jj < 16; ++jj) {
            const int j = (w << 4) + jj;
            const float* ws = &W_self [j * D + c * 16];   // uniform contiguous
            const float* wn = &W_neigh[j * D + c * 16];   // -> s_load_dwordx16
            #pragma unroll
            for (int u = 0; u < 16; ++u) {
                acc[jj] = fmaf(fr[u], ws[u], acc[jj]);
                acc[jj] = fmaf(hr[u], wn[u], acc[jj]);
            }
        }
    }

    // ---- output via LDS transpose (reuse fT), coalesced stores ----
    __syncthreads();                             // all waves done reading fT
    #pragma unroll
    for (int jj = 0; jj < 16; ++jj) {
        float o = acc[jj];
        o = act ? fmaxf(o, 0.0f) : o;
        fT[(w << 4) + jj][nl] = o;               // oT[j][n]
    }
    __syncthreads();
    #pragma unroll
    for (int r = 0; r < 16; ++r) {
        const int idx = r * 256 + tid;
        const int nl2 = idx >> 6;
        const int j   = idx & 63;
        const int n2  = n_base + nl2;
        if (n2 < N_NODES) out[n2 * D + j] = fT[j][nl2];
    }
}

// ---------------------------------------------------------------------------
extern "C" void kernel_launch(void* const* d_in, const int* in_sizes, int n_in,
                              void* d_out, int out_size, void* d_ws, size_t ws_size,
                              hipStream_t stream)
{
    const float* feat    = (const float*)d_in[0];
    const int*   src     = (const int*)  d_in[1];
    const int*   dst     = (const int*)  d_in[2];
    const float* W_self  = (const float*)d_in[3];
    const float* b_self  = (const float*)d_in[4];
    const float* W_neigh = (const float*)d_in[5];
    const float* b_neigh = (const float*)d_in[6];
    const int*   actf    = (const int*)  d_in[7];
    float* out = (float*)d_out;

    // Workspace layout (bytes):
    //   [0,        200000)  deg        int[50000]
    //   [200000,   400000)  row_start  int[50000]
    //   [400000,   400256)  blocksums  int[64]
    //   [400256,  3600256)  rank       int[800000]
    //   [3600256, 6800256)  src_sorted int[800000]
    char* base = (char*)d_ws;
    int* deg        = (int*)(base);
    int* row_start  = (int*)(base + 200000);
    int* blocksums  = (int*)(base + 400000);
    int* rank       = (int*)(base + 400256);
    int* src_sorted = (int*)(base + 3600256);

    hipMemsetAsync(deg, 0, 200000, stream);      // deg only

    const int e4blocks = (N_EDGES / 4 + 255) / 256;          // 782
    k_hist<<<e4blocks, 256, 0, stream>>>(dst, deg, rank);
    k_scan_blocks<<<NUM_SCAN_BLOCKS, SCAN_BLOCK, 0, stream>>>(deg, row_start, blocksums);
    k_scan_add<<<NUM_SCAN_BLOCKS, SCAN_BLOCK, 0, stream>>>(row_start, blocksums);
    k_fill<<<e4blocks, 256, 0, stream>>>(src, dst, rank, row_start, src_sorted);

    const int fblocks = (N_NODES + NPB - 1) / NPB;           // 782
    k_fused<<<fblocks, 256, 0, stream>>>(feat, row_start, deg, src_sorted,
                                         W_self, b_self, W_neigh, b_neigh,
                                         actf, out);
}

// Round 8
// 195.575 us; speedup vs baseline: 4.3564x; 1.0001x over previous
//
#include <hip/hip_runtime.h>

// SAGEConv: h_neigh = segment_mean(feat[src] -> dst); out = relu(feat@Ws^T + bs + h_neigh@Wn^T + bn)
// N=50000, E=800000, D_in = D_out = 64, fp32.
//
// Round 8: (a) k_fused 256->512 threads (8 waves/block): occupancy was
// grid-limited at 12 waves/CU (28% meas), gather is latency-bound -> double
// the wave pool, halve per-wave serial node loop; (b) replace full-array
// scan_add with a 1-block 64-lane shfl scan of 49 blocksums (bs_prefix),
// consumers add bs_prefix[node>>10].

#define N_NODES 50000
#define N_EDGES 800000
#define D 64
#define NPB 64                    // nodes per fused block
#define TPB 512                   // 8 waves
#define SCAN_BLOCK 1024
#define NUM_SCAN_BLOCKS ((N_NODES + SCAN_BLOCK - 1) / SCAN_BLOCK)   // 49

// ---------------------------------------------------------------------------
// K1: in-degree histogram + per-edge rank capture (4 edges/thread)
// ---------------------------------------------------------------------------
__global__ __launch_bounds__(256) void k_hist(const int* __restrict__ dst,
                                              int* __restrict__ deg,
                                              int* __restrict__ rank)
{
    const int e4 = blockIdx.x * 256 + threadIdx.x;
    if (e4 >= N_EDGES / 4) return;
    const int4 d = *reinterpret_cast<const int4*>(dst + e4 * 4);
    int4 r;
    r.x = atomicAdd(&deg[d.x], 1);
    r.y = atomicAdd(&deg[d.y], 1);
    r.z = atomicAdd(&deg[d.z], 1);
    r.w = atomicAdd(&deg[d.w], 1);
    *reinterpret_cast<int4*>(rank + e4 * 4) = r;
}

// ---------------------------------------------------------------------------
// K2a: per-block exclusive scan (Hillis-Steele over 1024) + block sums.
// row_start stays BLOCK-LOCAL exclusive; global offset comes from bs_prefix.
// ---------------------------------------------------------------------------
__global__ __launch_bounds__(SCAN_BLOCK) void k_scan_blocks(
    const int* __restrict__ deg,
    int* __restrict__ row_start,
    int* __restrict__ blocksums)
{
    __shared__ int s[SCAN_BLOCK];
    const int t = threadIdx.x;
    const int i = blockIdx.x * SCAN_BLOCK + t;
    const int orig = (i < N_NODES) ? deg[i] : 0;
    s[t] = orig;
    __syncthreads();
    for (int off = 1; off < SCAN_BLOCK; off <<= 1) {
        const int add = (t >= off) ? s[t - off] : 0;
        __syncthreads();
        s[t] += add;
        __syncthreads();
    }
    if (i < N_NODES) row_start[i] = s[t] - orig;       // exclusive within block
    if (t == SCAN_BLOCK - 1) blocksums[blockIdx.x] = s[t];
}

// ---------------------------------------------------------------------------
// K2b: 1 block, 64 lanes — exclusive shfl-scan of the 49 blocksums
// ---------------------------------------------------------------------------
__global__ __launch_bounds__(64) void k_scan_l2(const int* __restrict__ blocksums,
                                                int* __restrict__ bs_prefix)
{
    const int t = threadIdx.x;
    const int orig = (t < NUM_SCAN_BLOCKS) ? blocksums[t] : 0;
    int v = orig;
    #pragma unroll
    for (int off = 1; off < 64; off <<= 1) {
        const int u = __shfl_up(v, off);
        if (t >= off) v += u;
    }
    if (t < NUM_SCAN_BLOCKS) bs_prefix[t] = v - orig;  // exclusive
}

// ---------------------------------------------------------------------------
// K3: fill CSR slots — atomic-free (rank precomputed in k_hist)
// ---------------------------------------------------------------------------
__global__ __launch_bounds__(256) void k_fill(const int* __restrict__ src,
                                              const int* __restrict__ dst,
                                              const int* __restrict__ rank,
                                              const int* __restrict__ row_start,
                                              const int* __restrict__ bs_prefix,
                                              int* __restrict__ src_sorted)
{
    const int e4 = blockIdx.x * 256 + threadIdx.x;
    if (e4 >= N_EDGES / 4) return;
    const int4 s = *reinterpret_cast<const int4*>(src + e4 * 4);
    const int4 d = *reinterpret_cast<const int4*>(dst + e4 * 4);
    const int4 r = *reinterpret_cast<const int4*>(rank + e4 * 4);
    src_sorted[row_start[d.x] + bs_prefix[d.x >> 10] + r.x] = s.x;
    src_sorted[row_start[d.y] + bs_prefix[d.y >> 10] + r.y] = s.y;
    src_sorted[row_start[d.z] + bs_prefix[d.z >> 10] + r.z] = s.z;
    src_sorted[row_start[d.w] + bs_prefix[d.w >> 10] + r.w] = s.w;
}

// ---------------------------------------------------------------------------
// K4: fused gather-mean + transform. Block = 512 threads = 8 waves, 64 nodes.
// Gather: wave w handles 8 nodes; 16 lanes/edge, float4 loads (4 edges in
//   flight), shfl-broadcast indices, xor-reduce across slot groups.
// Transform: lane = node, wave w computes outputs j in [8w, 8w+8);
//   weights via wave-uniform contiguous scalar loads, f/h columns from LDS
//   ([i][n] layout, +1 pad, conflict-free).
// Output: LDS transpose round-trip (reuse fT) -> coalesced stores.
// ---------------------------------------------------------------------------
__global__ __launch_bounds__(TPB) void k_fused(
    const float* __restrict__ feat,
    const int* __restrict__ row_start,
    const int* __restrict__ bs_prefix,
    const int* __restrict__ deg,
    const int* __restrict__ src_sorted,
    const float* __restrict__ W_self,
    const float* __restrict__ b_self,
    const float* __restrict__ W_neigh,
    const float* __restrict__ b_neigh,
    const int* __restrict__ act_flag,
    float* __restrict__ out)
{
    __shared__ float fT[D][NPB + 1];   // fT[i][n_local], +1 pad
    __shared__ float hT[D][NPB + 1];

    const int tid  = threadIdx.x;
    const int lane = tid & 63;
    const int w    = __builtin_amdgcn_readfirstlane(tid >> 6);   // wave 0..7
    const int n_base = blockIdx.x * NPB;

    // ---- stage fT (transposed feat tile), coalesced reads ----
    #pragma unroll
    for (int r = 0; r < 8; ++r) {
        const int idx = r * TPB + tid;
        const int nl  = idx >> 6;
        const int i   = idx & 63;
        const int n   = n_base + nl;
        fT[i][nl] = (n < N_NODES) ? feat[n * D + i] : 0.0f;
    }

    // ---- gather-mean: wave w -> nodes nl = 8w .. 8w+7 ----
    const int slot = lane >> 4;          // edge slot 0..3
    const int d4   = (lane & 15) << 2;   // dim quad 0,4,...,60
    for (int q = 0; q < 8; ++q) {
        const int nl = (w << 3) + q;
        const int n  = n_base + nl;      // wave-uniform
        float4 a = make_float4(0.f, 0.f, 0.f, 0.f);
        int dg = 0;
        if (n < N_NODES) {
            const int start = row_start[n] + bs_prefix[n >> 10];  // uniform s_loads
            dg = deg[n];
            int my_idx = 0;
            if (lane < dg) my_idx = src_sorted[start + lane];   // one coalesced load
            const int kmax  = (dg < 64) ? dg : 64;
            const int iters = (kmax + 3) >> 2;                  // uniform trip count
            #pragma unroll 2
            for (int t2 = 0; t2 < iters; ++t2) {
                const int k  = (t2 << 2) + slot;
                const int kc = (k < kmax) ? k : 0;
                const int s  = __shfl(my_idx, kc);
                const float m = (k < kmax) ? 1.0f : 0.0f;
                const float4 v = *reinterpret_cast<const float4*>(feat + s * D + d4);
                a.x = fmaf(m, v.x, a.x);
                a.y = fmaf(m, v.y, a.y);
                a.z = fmaf(m, v.z, a.z);
                a.w = fmaf(m, v.w, a.w);
            }
            for (int k = 64 + slot; k < dg; k += 4) {           // dg>64: rare
                const int s = src_sorted[start + k];
                const float4 v = *reinterpret_cast<const float4*>(feat + s * D + d4);
                a.x += v.x; a.y += v.y; a.z += v.z; a.w += v.w;
            }
        }
        // reduce across the 4 slot groups
        a.x += __shfl_xor(a.x, 16); a.x += __shfl_xor(a.x, 32);
        a.y += __shfl_xor(a.y, 16); a.y += __shfl_xor(a.y, 32);
        a.z += __shfl_xor(a.z, 16); a.z += __shfl_xor(a.z, 32);
        a.w += __shfl_xor(a.w, 16); a.w += __shfl_xor(a.w, 32);
        const float inv = (dg > 0) ? (1.0f / (float)dg) : 0.0f;
        // lane writes component `slot` of its dim quad (2 lanes/bank = free)
        const float v = (slot & 1) ? ((slot & 2) ? a.w : a.y)
                                   : ((slot & 2) ? a.z : a.x);
        hT[d4 + slot][nl] = v * inv;
    }
    __syncthreads();

    // ---- transform: lane = node, wave w -> outputs j = 8w + jj ----
    const int nl = lane;
    const int act = act_flag[0];                 // uniform
    float acc[8];
    #pragma unroll
    for (int jj = 0; jj < 8; ++jj) {
        const int j = (w << 3) + jj;
        acc[jj] = b_self[j] + b_neigh[j];        // uniform s_loads
    }
    #pragma unroll
    for (int c = 0; c < 4; ++c) {                // i-chunks of 16
        float fr[16], hr[16];
        #pragma unroll
        for (int u = 0; u < 16; ++u) {
            fr[u] = fT[c * 16 + u][nl];          // conflict-free b32
            hr[u] = hT[c * 16 + u][nl];
        }
        #pragma unroll
        for (int jj = 0; jj < 8; ++jj) {
            const int j = (w << 3) + jj;
            const float* ws = &W_self [j * D + c * 16];   // uniform contiguous
            const float* wn = &W_neigh[j * D + c * 16];   // -> s_load wide
            #pragma unroll
            for (int u = 0; u < 16; ++u) {
                acc[jj] = fmaf(fr[u], ws[u], acc[jj]);
                acc[jj] = fmaf(hr[u], wn[u], acc[jj]);
            }
        }
    }

    // ---- output via LDS transpose (reuse fT), coalesced stores ----
    __syncthreads();                             // all waves done reading fT
    #pragma unroll
    for (int jj = 0; jj < 8; ++jj) {
        float o = acc[jj];
        o = act ? fmaxf(o, 0.0f) : o;
        fT[(w << 3) + jj][nl] = o;               // oT[j][n]
    }
    __syncthreads();
    #pragma unroll
    for (int r = 0; r < 8; ++r) {
        const int idx = r * TPB + tid;
        const int nl2 = idx >> 6;
        const int j   = idx & 63;
        const int n2  = n_base + nl2;
        if (n2 < N_NODES) out[n2 * D + j] = fT[j][nl2];
    }
}

// ---------------------------------------------------------------------------
extern "C" void kernel_launch(void* const* d_in, const int* in_sizes, int n_in,
                              void* d_out, int out_size, void* d_ws, size_t ws_size,
                              hipStream_t stream)
{
    const float* feat    = (const float*)d_in[0];
    const int*   src     = (const int*)  d_in[1];
    const int*   dst     = (const int*)  d_in[2];
    const float* W_self  = (const float*)d_in[3];
    const float* b_self  = (const float*)d_in[4];
    const float* W_neigh = (const float*)d_in[5];
    const float* b_neigh = (const float*)d_in[6];
    const int*   actf    = (const int*)  d_in[7];
    float* out = (float*)d_out;

    // Workspace layout (bytes):
    //   [0,        200000)  deg        int[50000]
    //   [200000,   400000)  row_start  int[50000]  (block-local exclusive)
    //   [400000,   400256)  blocksums  int[64]
    //   [400256,   400512)  bs_prefix  int[64]
    //   [400512,  3600512)  rank       int[800000]
    //   [3600512, 6800512)  src_sorted int[800000]
    char* base = (char*)d_ws;
    int* deg        = (int*)(base);
    int* row_start  = (int*)(base + 200000);
    int* blocksums  = (int*)(base + 400000);
    int* bs_prefix  = (int*)(base + 400256);
    int* rank       = (int*)(base + 400512);
    int* src_sorted = (int*)(base + 3600512);

    hipMemsetAsync(deg, 0, 200000, stream);      // deg only

    const int e4blocks = (N_EDGES / 4 + 255) / 256;          // 782
    k_hist<<<e4blocks, 256, 0, stream>>>(dst, deg, rank);
    k_scan_blocks<<<NUM_SCAN_BLOCKS, SCAN_BLOCK, 0, stream>>>(deg, row_start, blocksums);
    k_scan_l2<<<1, 64, 0, stream>>>(blocksums, bs_prefix);
    k_fill<<<e4blocks, 256, 0, stream>>>(src, dst, rank, row_start, bs_prefix, src_sorted);

    const int fblocks = (N_NODES + NPB - 1) / NPB;           // 782
    k_fused<<<fblocks, TPB, 0, stream>>>(feat, row_start, bs_prefix, deg, src_sorted,
                                         W_self, b_self, W_neigh, b_neigh,
                                         actf, out);
}